// Round 6
// baseline (350.513 us; speedup 1.0000x reference)
//
#include <hip/hip_runtime.h>
#include <stdint.h>

// Algebra (validated R3-R5): only the cls token queries.
//   q = x0 @ Wq + bq                                   (256 x 512)
//   r_h[j] = sum_c q[h*64+c] * Wk[j][h*64+c]  == q @ Wk^T blockdiag
//   logits_h[n] = (r_h . x_n)/8   (q.bk const dropped: softmax-invariant)
//   p = softmax ; y_h = sum_n p_h[n] x[n]              (Y: 256 x 4096)
//   ctx_h = y_h @ Wv[:, h-slice] + bv ; out = ctx @ Wo + bo
// R6: single-pass flash fusion for logits/softmax/y; all small GEMMs at
// >=512 blocks (2/CU); Wk pre-transposed for coalesced r-projection. fp32.

// ---------------- K0: WkT[c][j] = Wk[j][c] ----------------
__global__ __launch_bounds__(256) void transpose_kernel(
    const float* __restrict__ Wk, float* __restrict__ WkT) {
  const int j0 = blockIdx.x * 32;
  const int c0 = blockIdx.y * 32;
  const int t = threadIdx.x;
  __shared__ float tile[32][33];

  {
    const int row = t >> 3;          // 0..31 (j-local)
    const int c4 = (t & 7) * 4;      // 0..28 (c-local)
    float4 v = *(const float4*)&Wk[(long)(j0 + row) * 512 + c0 + c4];
    tile[row][c4] = v.x; tile[row][c4 + 1] = v.y;
    tile[row][c4 + 2] = v.z; tile[row][c4 + 3] = v.w;
  }
  __syncthreads();
  {
    const int row = t >> 3;          // c-local
    const int j4 = (t & 7) * 4;      // j-local
    float4 v = make_float4(tile[j4][row], tile[j4 + 1][row],
                           tile[j4 + 2][row], tile[j4 + 3][row]);
    *(float4*)&WkT[(long)(c0 + row) * 512 + j0 + j4] = v;
  }
}

// ---------------- K1/K4/K5: generic C[256x512] = A @ W + bias ----------------
// grid (64 rt x 4 rows, 8 jt x 64 cols). A row stride + per-jt col offset
// parameterized so one kernel serves q-proj, ctx-proj (blockdiag), out-proj.
__global__ __launch_bounds__(256) void gemm_rc_kernel(
    const float* __restrict__ A, long a_row_stride, int a_col_off_mult,
    const float* __restrict__ W, const float* __restrict__ bias,
    float* __restrict__ C) {
  const int rt = blockIdx.x;
  const int jt = blockIdx.y;
  const int t = threadIdx.x;
  __shared__ float a_s[4][512];

#pragma unroll
  for (int l = 0; l < 2; ++l) {
    int flat4 = t + l * 256;           // 0..511
    int arow = flat4 >> 7;             // 0..3
    int k4 = (flat4 & 127) * 4;        // 0..508
    float4 v = *(const float4*)&A[(long)(rt * 4 + arow) * a_row_stride +
                                  (long)jt * a_col_off_mult + k4];
    a_s[arow][k4] = v.x; a_s[arow][k4 + 1] = v.y;
    a_s[arow][k4 + 2] = v.z; a_s[arow][k4 + 3] = v.w;
  }
  __syncthreads();

  const int col = t & 63;
  const int rw = t >> 6;
  const int j = jt * 64 + col;
  float acc = bias[j];
#pragma unroll 8
  for (int k = 0; k < 512; ++k)
    acc += a_s[rw][k] * W[(long)k * 512 + j];
  C[(long)(rt * 4 + rw) * 512 + j] = acc;
}

// ---------------- K2: r[256][4096] blockdiag: r[s][h*512+jp] ----------------
// grid (64 rt x 4 rows, 8 h). K=64 over head channels, WkT coalesced.
__global__ __launch_bounds__(256) void r_kernel(
    const float* __restrict__ q, const float* __restrict__ WkT,
    float* __restrict__ r_all) {
  const int rt = blockIdx.x;
  const int h = blockIdx.y;
  const int t = threadIdx.x;
  __shared__ float q_s[4][64];

  if (t < 256) {
    int row = t >> 6, c = t & 63;
    q_s[row][c] = q[(long)(rt * 4 + row) * 512 + h * 64 + c];
  }
  __syncthreads();

  const int jp4 = (t & 127) * 4;      // 0..508
  const int rh = t >> 7;              // 0..1 -> rows rh*2, rh*2+1
  float4 acc0 = make_float4(0.f, 0.f, 0.f, 0.f);
  float4 acc1 = make_float4(0.f, 0.f, 0.f, 0.f);
#pragma unroll 8
  for (int c = 0; c < 64; ++c) {
    float4 w4 = *(const float4*)&WkT[(long)(h * 64 + c) * 512 + jp4];
    float q0 = q_s[rh * 2][c], q1 = q_s[rh * 2 + 1][c];
    acc0.x += q0 * w4.x; acc0.y += q0 * w4.y; acc0.z += q0 * w4.z; acc0.w += q0 * w4.w;
    acc1.x += q1 * w4.x; acc1.y += q1 * w4.y; acc1.z += q1 * w4.z; acc1.w += q1 * w4.w;
  }
  *(float4*)&r_all[(long)(rt * 4 + rh * 2) * 4096 + h * 512 + jp4] = acc0;
  *(float4*)&r_all[(long)(rt * 4 + rh * 2 + 1) * 4096 + h * 512 + jp4] = acc1;
}

// ---------------- K3: flash — logits + softmax + Y in one x-pass -------------
// grid 256 (one block per bs), 1024 threads (16 waves).
__global__ __launch_bounds__(1024) void flash_kernel(
    const float* __restrict__ x, const float* __restrict__ r_all,
    float* __restrict__ Y) {
  const int bs = blockIdx.x;
  const int t = threadIdx.x;
  const int w = t >> 6, lane = t & 63;
  __shared__ float ls[8][256];   // logits, then p in place

  // ---- phase 1: logits. wave w owns tokens w*16..w*16+15 ----
  {
    float rv[8][8];
    const float* rb = r_all + (long)bs * 4096 + lane * 8;
#pragma unroll
    for (int h = 0; h < 8; ++h) {
      float4 a = *(const float4*)&rb[h * 512];
      float4 b = *(const float4*)&rb[h * 512 + 4];
      rv[h][0] = a.x; rv[h][1] = a.y; rv[h][2] = a.z; rv[h][3] = a.w;
      rv[h][4] = b.x; rv[h][5] = b.y; rv[h][6] = b.z; rv[h][7] = b.w;
    }
    const float* xw = x + ((long)bs * 256 + w * 16) * 512 + lane * 8;
    float4 xa = *(const float4*)xw;
    float4 xb = *(const float4*)(xw + 4);
    for (int i = 0; i < 16; ++i) {
      float4 ca = xa, cb = xb;
      if (i < 15) {                      // prefetch next token
        xa = *(const float4*)(xw + (long)(i + 1) * 512);
        xb = *(const float4*)(xw + (long)(i + 1) * 512 + 4);
      }
      float acc[8];
#pragma unroll
      for (int h = 0; h < 8; ++h)
        acc[h] = ca.x * rv[h][0] + ca.y * rv[h][1] + ca.z * rv[h][2] + ca.w * rv[h][3]
               + cb.x * rv[h][4] + cb.y * rv[h][5] + cb.z * rv[h][6] + cb.w * rv[h][7];
#pragma unroll
      for (int h = 0; h < 8; ++h)
        for (int off = 32; off; off >>= 1)
          acc[h] += __shfl_xor(acc[h], off);
      if (lane < 8) {
        float v = acc[0];
#pragma unroll
        for (int h = 1; h < 8; ++h) v = (lane == h) ? acc[h] : v;
        ls[lane][w * 16 + i] = v * 0.125f;
      }
    }
  }
  __syncthreads();

  // ---- phase 2: softmax per head, in place. wave w<8 -> head w ----
  if (w < 8) {
    const int h = w;
    float4 l4 = *(const float4*)&ls[h][lane * 4];
    float m = fmaxf(fmaxf(l4.x, l4.y), fmaxf(l4.z, l4.w));
    for (int o = 32; o; o >>= 1) m = fmaxf(m, __shfl_xor(m, o));
    float e0 = __expf(l4.x - m), e1 = __expf(l4.y - m);
    float e2 = __expf(l4.z - m), e3 = __expf(l4.w - m);
    float s = e0 + e1 + e2 + e3;
    for (int o = 32; o; o >>= 1) s += __shfl_xor(s, o);
    const float inv = 1.f / s;
    *(float4*)&ls[h][lane * 4] = make_float4(e0 * inv, e1 * inv, e2 * inv, e3 * inv);
  }
  __syncthreads();

  // ---- phase 3: Y[bs][h*512+d] = sum_n p[h][n] x[n][d]. threads t<512 ----
  if (t < 512) {
    const int d = t;
    float acc[8] = {};
    const float* xb2 = x + (long)bs * 256 * 512 + d;
#pragma unroll 4
    for (int n0 = 0; n0 < 256; n0 += 4) {
      float xv0 = xb2[(long)(n0 + 0) * 512];
      float xv1 = xb2[(long)(n0 + 1) * 512];
      float xv2 = xb2[(long)(n0 + 2) * 512];
      float xv3 = xb2[(long)(n0 + 3) * 512];
#pragma unroll
      for (int h = 0; h < 8; ++h) {
        float4 p4 = *(const float4*)&ls[h][n0];
        acc[h] += p4.x * xv0 + p4.y * xv1 + p4.z * xv2 + p4.w * xv3;
      }
    }
#pragma unroll
    for (int h = 0; h < 8; ++h)
      Y[(long)bs * 4096 + h * 512 + d] = acc[h];
  }
}

extern "C" void kernel_launch(void* const* d_in, const int* in_sizes, int n_in,
                              void* d_out, int out_size, void* d_ws, size_t ws_size,
                              hipStream_t stream) {
  (void)in_sizes; (void)n_in; (void)out_size; (void)ws_size;
  const float* x  = (const float*)d_in[0];
  const float* Wq = (const float*)d_in[1];
  const float* bq = (const float*)d_in[2];
  const float* Wk = (const float*)d_in[3];
  const float* bk = (const float*)d_in[4];  (void)bk;  // softmax-invariant
  const float* Wv = (const float*)d_in[5];
  const float* bv = (const float*)d_in[6];
  const float* Wo = (const float*)d_in[7];
  const float* bo = (const float*)d_in[8];
  float* out = (float*)d_out;

  float* WkT = (float*)d_ws;       // 512*512  = 1 MiB
  float* q   = WkT + 262144;       // 256*512  = 0.5 MiB
  float* r   = q + 131072;         // 256*4096 = 4 MiB
  float* Y   = r + 1048576;        // 256*4096 = 4 MiB
  float* ctx = Y + 1048576;        // 256*512  = 0.5 MiB

  transpose_kernel<<<dim3(16, 16), 256, 0, stream>>>(Wk, WkT);
  // q = x0 @ Wq + bq   (x cls rows, stride 256*512)
  gemm_rc_kernel<<<dim3(64, 8), 256, 0, stream>>>(x, 131072L, 0, Wq, bq, q);
  r_kernel<<<dim3(64, 8), 256, 0, stream>>>(q, WkT, r);
  flash_kernel<<<256, 1024, 0, stream>>>(x, r, Y);
  // ctx_h = y_h @ Wv[:, h-slice] + bv  (A col offset jt*512, blockdiag)
  gemm_rc_kernel<<<dim3(64, 8), 256, 0, stream>>>(Y, 4096L, 512, Wv, bv, ctx);
  // out = ctx @ Wo + bo
  gemm_rc_kernel<<<dim3(64, 8), 256, 0, stream>>>(ctx, 512L, 0, Wo, bo, out);
}

// Round 7
// 302.245 us; speedup vs baseline: 1.1597x; 1.1597x over previous
//
#include <hip/hip_runtime.h>
#include <stdint.h>

// Algebra (validated R3-R6): only the cls token queries.
//   q = x0 @ Wq + bq ; r_h = q_h @ Wk_h^T (blockdiag) ; logits = (r . x_n)/8
//   p = softmax ; y_h = sum_n p_h[n] x[n] ; ctx_h = y_h @ Wv_h + bv ; out = ctx @ Wo + bo
// R7: flash split into logits (2048 blocks, 10-shfl vector-split reduction)
// + y (1024 blocks, n-split). Small GEMMs unchanged from R6. All fp32.

// ---------------- K0: WkT[c][j] = Wk[j][c] ----------------
__global__ __launch_bounds__(256) void transpose_kernel(
    const float* __restrict__ Wk, float* __restrict__ WkT) {
  const int j0 = blockIdx.x * 32;
  const int c0 = blockIdx.y * 32;
  const int t = threadIdx.x;
  __shared__ float tile[32][33];
  {
    const int row = t >> 3;
    const int c4 = (t & 7) * 4;
    float4 v = *(const float4*)&Wk[(long)(j0 + row) * 512 + c0 + c4];
    tile[row][c4] = v.x; tile[row][c4 + 1] = v.y;
    tile[row][c4 + 2] = v.z; tile[row][c4 + 3] = v.w;
  }
  __syncthreads();
  {
    const int row = t >> 3;
    const int j4 = (t & 7) * 4;
    float4 v = make_float4(tile[j4][row], tile[j4 + 1][row],
                           tile[j4 + 2][row], tile[j4 + 3][row]);
    *(float4*)&WkT[(long)(c0 + row) * 512 + j0 + j4] = v;
  }
}

// ---------------- generic C[256x512] = A @ W + bias ----------------
__global__ __launch_bounds__(256) void gemm_rc_kernel(
    const float* __restrict__ A, long a_row_stride, int a_col_off_mult,
    const float* __restrict__ W, const float* __restrict__ bias,
    float* __restrict__ C) {
  const int rt = blockIdx.x;
  const int jt = blockIdx.y;
  const int t = threadIdx.x;
  __shared__ float a_s[4][512];

#pragma unroll
  for (int l = 0; l < 2; ++l) {
    int flat4 = t + l * 256;
    int arow = flat4 >> 7;
    int k4 = (flat4 & 127) * 4;
    float4 v = *(const float4*)&A[(long)(rt * 4 + arow) * a_row_stride +
                                  (long)jt * a_col_off_mult + k4];
    a_s[arow][k4] = v.x; a_s[arow][k4 + 1] = v.y;
    a_s[arow][k4 + 2] = v.z; a_s[arow][k4 + 3] = v.w;
  }
  __syncthreads();

  const int col = t & 63;
  const int rw = t >> 6;
  const int j = jt * 64 + col;
  float acc = bias[j];
#pragma unroll 16
  for (int k = 0; k < 512; ++k)
    acc += a_s[rw][k] * W[(long)k * 512 + j];
  C[(long)(rt * 4 + rw) * 512 + j] = acc;
}

// ---------------- r[256][4096]: r[s][h*512+jp] = q_h . WkT cols ----------------
__global__ __launch_bounds__(256) void r_kernel(
    const float* __restrict__ q, const float* __restrict__ WkT,
    float* __restrict__ r_all) {
  const int rt = blockIdx.x;
  const int h = blockIdx.y;
  const int t = threadIdx.x;
  __shared__ float q_s[4][64];

  {
    int row = t >> 6, c = t & 63;
    q_s[row][c] = q[(long)(rt * 4 + row) * 512 + h * 64 + c];
  }
  __syncthreads();

  const int jp4 = (t & 127) * 4;
  const int rh = t >> 7;
  float4 acc0 = make_float4(0.f, 0.f, 0.f, 0.f);
  float4 acc1 = make_float4(0.f, 0.f, 0.f, 0.f);
#pragma unroll 8
  for (int c = 0; c < 64; ++c) {
    float4 w4 = *(const float4*)&WkT[(long)(h * 64 + c) * 512 + jp4];
    float q0 = q_s[rh * 2][c], q1 = q_s[rh * 2 + 1][c];
    acc0.x += q0 * w4.x; acc0.y += q0 * w4.y; acc0.z += q0 * w4.z; acc0.w += q0 * w4.w;
    acc1.x += q1 * w4.x; acc1.y += q1 * w4.y; acc1.z += q1 * w4.z; acc1.w += q1 * w4.w;
  }
  *(float4*)&r_all[(long)(rt * 4 + rh * 2) * 4096 + h * 512 + jp4] = acc0;
  *(float4*)&r_all[(long)(rt * 4 + rh * 2 + 1) * 4096 + h * 512 + jp4] = acc1;
}

// ---------------- logits: grid (256 bs, 8 nt) x 256 thr ----------------
// wave w owns 8 tokens; 8-head dot reduced with vector-splitting butterfly
// (7 shfl in-group + 3 cross-group = 10 shfl/token vs 48 naive).
__global__ __launch_bounds__(256) void logits_kernel(
    const float* __restrict__ x, const float* __restrict__ r_all,
    float* __restrict__ L) {
  const int bs = blockIdx.x;
  const int nt = blockIdx.y;
  const int t = threadIdx.x;
  const int w = t >> 6, lane = t & 63;

  float rv[8][8];
  const float* rb = r_all + (long)bs * 4096 + lane * 8;
#pragma unroll
  for (int h = 0; h < 8; ++h) {
    float4 a = *(const float4*)&rb[h * 512];
    float4 b = *(const float4*)&rb[h * 512 + 4];
    rv[h][0] = a.x; rv[h][1] = a.y; rv[h][2] = a.z; rv[h][3] = a.w;
    rv[h][4] = b.x; rv[h][5] = b.y; rv[h][6] = b.z; rv[h][7] = b.w;
  }

  const int l4 = lane & 4, l2 = lane & 2, l1 = lane & 1;
#pragma unroll 2
  for (int i = 0; i < 8; ++i) {
    const int n = nt * 32 + w * 8 + i;
    const float* xr = x + ((long)bs * 256 + n) * 512 + lane * 8;
    float4 xa = *(const float4*)xr;
    float4 xb = *(const float4*)(xr + 4);
    float acc[8];
#pragma unroll
    for (int h = 0; h < 8; ++h)
      acc[h] = xa.x * rv[h][0] + xa.y * rv[h][1] + xa.z * rv[h][2] + xa.w * rv[h][3]
             + xb.x * rv[h][4] + xb.y * rv[h][5] + xb.z * rv[h][6] + xb.w * rv[h][7];
    // step m=4: low lanes keep heads 0-3, high lanes heads 4-7
#pragma unroll
    for (int j = 0; j < 4; ++j) {
      float v = l4 ? acc[j] : acc[j + 4];
      float tt = __shfl_xor(v, 4);
      acc[j] = (l4 ? acc[j + 4] : acc[j]) + tt;
    }
    // step m=2
#pragma unroll
    for (int j = 0; j < 2; ++j) {
      float v = l2 ? acc[j] : acc[j + 2];
      float tt = __shfl_xor(v, 2);
      acc[j] = (l2 ? acc[j + 2] : acc[j]) + tt;
    }
    // step m=1
    {
      float v = l1 ? acc[0] : acc[1];
      float tt = __shfl_xor(v, 1);
      acc[0] = (l1 ? acc[1] : acc[0]) + tt;
    }
    // cross-group (8 groups of 8 lanes)
    acc[0] += __shfl_xor(acc[0], 8);
    acc[0] += __shfl_xor(acc[0], 16);
    acc[0] += __shfl_xor(acc[0], 32);
    if (lane < 8)
      L[((long)bs * 8 + lane) * 256 + n] = acc[0] * 0.125f;
  }
}

// ---------------- y: grid (256 bs, 4 dt) x 256 thr, n-split halves ------------
__global__ __launch_bounds__(256) void y_kernel(
    const float* __restrict__ x, const float* __restrict__ L,
    float* __restrict__ Y) {
  const int bs = blockIdx.x;
  const int dt = blockIdx.y;
  const int t = threadIdx.x;
  const int w = t >> 6, lane = t & 63;
  __shared__ float p_s[8][256];
  __shared__ float yp[8][128];

  // softmax: wave w handles heads 2w, 2w+1
#pragma unroll
  for (int hh = 0; hh < 2; ++hh) {
    const int h = w * 2 + hh;
    float4 lv = *(const float4*)&L[((long)bs * 8 + h) * 256 + lane * 4];
    float m = fmaxf(fmaxf(lv.x, lv.y), fmaxf(lv.z, lv.w));
    for (int o = 32; o; o >>= 1) m = fmaxf(m, __shfl_xor(m, o));
    float e0 = __expf(lv.x - m), e1 = __expf(lv.y - m);
    float e2 = __expf(lv.z - m), e3 = __expf(lv.w - m);
    float s = e0 + e1 + e2 + e3;
    for (int o = 32; o; o >>= 1) s += __shfl_xor(s, o);
    const float inv = 1.f / s;
    *(float4*)&p_s[h][lane * 4] = make_float4(e0 * inv, e1 * inv, e2 * inv, e3 * inv);
  }
  __syncthreads();

  const int d = dt * 128 + (t & 127);
  const int half = t >> 7;           // n-range 0..127 or 128..255
  float acc[8] = {};
  const float* xb = x + ((long)bs * 256 + half * 128) * 512 + d;
#pragma unroll 4
  for (int n = 0; n < 128; ++n) {
    float xv = xb[(long)n * 512];
#pragma unroll
    for (int h = 0; h < 8; ++h)
      acc[h] += p_s[h][half * 128 + n] * xv;
  }
  if (half == 1) {
#pragma unroll
    for (int h = 0; h < 8; ++h) yp[h][t & 127] = acc[h];
  }
  __syncthreads();
  if (half == 0) {
#pragma unroll
    for (int h = 0; h < 8; ++h)
      Y[(long)bs * 4096 + h * 512 + d] = acc[h] + yp[h][t];
  }
}

extern "C" void kernel_launch(void* const* d_in, const int* in_sizes, int n_in,
                              void* d_out, int out_size, void* d_ws, size_t ws_size,
                              hipStream_t stream) {
  (void)in_sizes; (void)n_in; (void)out_size; (void)ws_size;
  const float* x  = (const float*)d_in[0];
  const float* Wq = (const float*)d_in[1];
  const float* bq = (const float*)d_in[2];
  const float* Wk = (const float*)d_in[3];
  const float* bk = (const float*)d_in[4];  (void)bk;  // softmax-invariant
  const float* Wv = (const float*)d_in[5];
  const float* bv = (const float*)d_in[6];
  const float* Wo = (const float*)d_in[7];
  const float* bo = (const float*)d_in[8];
  float* out = (float*)d_out;

  float* WkT = (float*)d_ws;       // 512*512  = 1 MiB
  float* q   = WkT + 262144;       // 256*512  = 0.5 MiB
  float* r   = q + 131072;         // 256*4096 = 4 MiB
  float* L   = r + 1048576;        // 256*8*256= 2 MiB
  float* Y   = L + 524288;         // 256*4096 = 4 MiB
  float* ctx = Y + 1048576;        // 256*512  = 0.5 MiB

  transpose_kernel<<<dim3(16, 16), 256, 0, stream>>>(Wk, WkT);
  gemm_rc_kernel<<<dim3(64, 8), 256, 0, stream>>>(x, 131072L, 0, Wq, bq, q);
  r_kernel<<<dim3(64, 8), 256, 0, stream>>>(q, WkT, r);
  logits_kernel<<<dim3(256, 8), 256, 0, stream>>>(x, r, L);
  y_kernel<<<dim3(256, 4), 256, 0, stream>>>(x, L, Y);
  gemm_rc_kernel<<<dim3(64, 8), 256, 0, stream>>>(Y, 4096L, 512, Wv, bv, ctx);
  gemm_rc_kernel<<<dim3(64, 8), 256, 0, stream>>>(ctx, 512L, 0, Wo, bo, out);
}

// Round 8
// 272.462 us; speedup vs baseline: 1.2865x; 1.1093x over previous
//
#include <hip/hip_runtime.h>
#include <stdint.h>

// Algebra (validated R3-R7): only the cls token queries.
//   q = x0 @ Wq + bq ; r_h = q_h @ Wk_h^T (blockdiag) ; logits = (r . x_n)/8
//   p = softmax ; y_h = sum_n p_h[n] x[n] ; ctx_h = y_h @ Wv_h + bv ; out = ctx @ Wo + bo
// R8: k-split gemm (4-row x 64-col block, waves own k-quarters, LDS reduce) for
// q/ctx/out; transpose+q merged into one launch. logits/y/r unchanged (proven).

// ---------------- gemm k-split body (shared by prep & standalone) ----------------
__device__ __forceinline__ void gemm_ks_body(
    const float* __restrict__ A, long a_row_stride, int a_col_off_mult,
    const float* __restrict__ W, const float* __restrict__ bias,
    float* __restrict__ C, int rt, int jt, int t,
    float (*a_s)[512], float (*red_s)[4][64]) {
  const int w = t >> 6, lane = t & 63;

  // stage A: 4 rows x 512
#pragma unroll
  for (int l = 0; l < 2; ++l) {
    int flat4 = t + l * 256;
    int arow = flat4 >> 7;
    int k4 = (flat4 & 127) * 4;
    float4 v = *(const float4*)&A[(long)(rt * 4 + arow) * a_row_stride +
                                  (long)jt * a_col_off_mult + k4];
    a_s[arow][k4] = v.x; a_s[arow][k4 + 1] = v.y;
    a_s[arow][k4 + 2] = v.z; a_s[arow][k4 + 3] = v.w;
  }
  __syncthreads();

  const int j = jt * 64 + lane;
  float acc0 = 0.f, acc1 = 0.f, acc2 = 0.f, acc3 = 0.f;
  const float* wp = W + (long)(w * 128) * 512 + j;
  const float* ap = &a_s[0][w * 128];
#pragma unroll 8
  for (int k = 0; k < 128; ++k) {
    float wv = wp[(long)k * 512];
    acc0 += ap[k] * wv;
    acc1 += ap[512 + k] * wv;
    acc2 += ap[1024 + k] * wv;
    acc3 += ap[1536 + k] * wv;
  }
  if (w > 0) {
    red_s[w - 1][0][lane] = acc0;
    red_s[w - 1][1][lane] = acc1;
    red_s[w - 1][2][lane] = acc2;
    red_s[w - 1][3][lane] = acc3;
  }
  __syncthreads();
  if (w == 0) {
#pragma unroll
    for (int rr = 0; rr < 3; ++rr) {
      acc0 += red_s[rr][0][lane];
      acc1 += red_s[rr][1][lane];
      acc2 += red_s[rr][2][lane];
      acc3 += red_s[rr][3][lane];
    }
    const float b = bias[j];
    C[(long)(rt * 4 + 0) * 512 + j] = acc0 + b;
    C[(long)(rt * 4 + 1) * 512 + j] = acc1 + b;
    C[(long)(rt * 4 + 2) * 512 + j] = acc2 + b;
    C[(long)(rt * 4 + 3) * 512 + j] = acc3 + b;
  }
}

// ---------------- K1: merged transpose (blocks 0-255) + q gemm (256-767) -------
__global__ __launch_bounds__(256) void prep_kernel(
    const float* __restrict__ x, const float* __restrict__ Wq,
    const float* __restrict__ bq, const float* __restrict__ Wk,
    float* __restrict__ WkT, float* __restrict__ q) {
  __shared__ float a_s[4][512];
  __shared__ float red_s[3][4][64];
  const int t = threadIdx.x;

  if (blockIdx.x < 256) {
    float (*tile)[64] = (float(*)[64])&a_s[0][0];   // 32x33 fits in 8KB
    const int j0 = (blockIdx.x & 15) * 32;
    const int c0 = (blockIdx.x >> 4) * 32;
    {
      const int row = t >> 3;
      const int c4 = (t & 7) * 4;
      float4 v = *(const float4*)&Wk[(long)(j0 + row) * 512 + c0 + c4];
      float* tr = &tile[0][0] + row * 33;
      tr[c4] = v.x; tr[c4 + 1] = v.y; tr[c4 + 2] = v.z; tr[c4 + 3] = v.w;
    }
    __syncthreads();
    {
      const int row = t >> 3;
      const int j4 = (t & 7) * 4;
      const float* tb = &tile[0][0];
      float4 v = make_float4(tb[j4 * 33 + row], tb[(j4 + 1) * 33 + row],
                             tb[(j4 + 2) * 33 + row], tb[(j4 + 3) * 33 + row]);
      *(float4*)&WkT[(long)(c0 + row) * 512 + j0 + j4] = v;
    }
  } else {
    const int bid = blockIdx.x - 256;
    const int rt = bid & 63;
    const int jt = bid >> 6;
    gemm_ks_body(x, 131072L, 0, Wq, bq, q, rt, jt, t, a_s, red_s);
  }
}

// ---------------- standalone k-split gemm (ctx, out) ----------------
__global__ __launch_bounds__(256) void gemm_ks_kernel(
    const float* __restrict__ A, long a_row_stride, int a_col_off_mult,
    const float* __restrict__ W, const float* __restrict__ bias,
    float* __restrict__ C) {
  __shared__ float a_s[4][512];
  __shared__ float red_s[3][4][64];
  gemm_ks_body(A, a_row_stride, a_col_off_mult, W, bias, C,
               blockIdx.x, blockIdx.y, threadIdx.x, a_s, red_s);
}

// ---------------- r[256][4096]: r[s][h*512+jp] = q_h . WkT cols ----------------
__global__ __launch_bounds__(256) void r_kernel(
    const float* __restrict__ q, const float* __restrict__ WkT,
    float* __restrict__ r_all) {
  const int rt = blockIdx.x;
  const int h = blockIdx.y;
  const int t = threadIdx.x;
  __shared__ float q_s[4][64];

  {
    int row = t >> 6, c = t & 63;
    q_s[row][c] = q[(long)(rt * 4 + row) * 512 + h * 64 + c];
  }
  __syncthreads();

  const int jp4 = (t & 127) * 4;
  const int rh = t >> 7;
  float4 acc0 = make_float4(0.f, 0.f, 0.f, 0.f);
  float4 acc1 = make_float4(0.f, 0.f, 0.f, 0.f);
#pragma unroll 8
  for (int c = 0; c < 64; ++c) {
    float4 w4 = *(const float4*)&WkT[(long)(h * 64 + c) * 512 + jp4];
    float q0 = q_s[rh * 2][c], q1 = q_s[rh * 2 + 1][c];
    acc0.x += q0 * w4.x; acc0.y += q0 * w4.y; acc0.z += q0 * w4.z; acc0.w += q0 * w4.w;
    acc1.x += q1 * w4.x; acc1.y += q1 * w4.y; acc1.z += q1 * w4.z; acc1.w += q1 * w4.w;
  }
  *(float4*)&r_all[(long)(rt * 4 + rh * 2) * 4096 + h * 512 + jp4] = acc0;
  *(float4*)&r_all[(long)(rt * 4 + rh * 2 + 1) * 4096 + h * 512 + jp4] = acc1;
}

// ---------------- logits: grid (256 bs, 8 nt) x 256 thr ----------------
__global__ __launch_bounds__(256) void logits_kernel(
    const float* __restrict__ x, const float* __restrict__ r_all,
    float* __restrict__ L) {
  const int bs = blockIdx.x;
  const int nt = blockIdx.y;
  const int t = threadIdx.x;
  const int w = t >> 6, lane = t & 63;

  float rv[8][8];
  const float* rb = r_all + (long)bs * 4096 + lane * 8;
#pragma unroll
  for (int h = 0; h < 8; ++h) {
    float4 a = *(const float4*)&rb[h * 512];
    float4 b = *(const float4*)&rb[h * 512 + 4];
    rv[h][0] = a.x; rv[h][1] = a.y; rv[h][2] = a.z; rv[h][3] = a.w;
    rv[h][4] = b.x; rv[h][5] = b.y; rv[h][6] = b.z; rv[h][7] = b.w;
  }

  const int l4 = lane & 4, l2 = lane & 2, l1 = lane & 1;
#pragma unroll 2
  for (int i = 0; i < 8; ++i) {
    const int n = nt * 32 + w * 8 + i;
    const float* xr = x + ((long)bs * 256 + n) * 512 + lane * 8;
    float4 xa = *(const float4*)xr;
    float4 xb = *(const float4*)(xr + 4);
    float acc[8];
#pragma unroll
    for (int h = 0; h < 8; ++h)
      acc[h] = xa.x * rv[h][0] + xa.y * rv[h][1] + xa.z * rv[h][2] + xa.w * rv[h][3]
             + xb.x * rv[h][4] + xb.y * rv[h][5] + xb.z * rv[h][6] + xb.w * rv[h][7];
#pragma unroll
    for (int j = 0; j < 4; ++j) {
      float v = l4 ? acc[j] : acc[j + 4];
      float tt = __shfl_xor(v, 4);
      acc[j] = (l4 ? acc[j + 4] : acc[j]) + tt;
    }
#pragma unroll
    for (int j = 0; j < 2; ++j) {
      float v = l2 ? acc[j] : acc[j + 2];
      float tt = __shfl_xor(v, 2);
      acc[j] = (l2 ? acc[j + 2] : acc[j]) + tt;
    }
    {
      float v = l1 ? acc[0] : acc[1];
      float tt = __shfl_xor(v, 1);
      acc[0] = (l1 ? acc[1] : acc[0]) + tt;
    }
    acc[0] += __shfl_xor(acc[0], 8);
    acc[0] += __shfl_xor(acc[0], 16);
    acc[0] += __shfl_xor(acc[0], 32);
    if (lane < 8)
      L[((long)bs * 8 + lane) * 256 + n] = acc[0] * 0.125f;
  }
}

// ---------------- y: grid (256 bs, 4 dt) x 256 thr, n-split halves ------------
__global__ __launch_bounds__(256) void y_kernel(
    const float* __restrict__ x, const float* __restrict__ L,
    float* __restrict__ Y) {
  const int bs = blockIdx.x;
  const int dt = blockIdx.y;
  const int t = threadIdx.x;
  const int w = t >> 6, lane = t & 63;
  __shared__ float p_s[8][256];
  __shared__ float yp[8][128];

#pragma unroll
  for (int hh = 0; hh < 2; ++hh) {
    const int h = w * 2 + hh;
    float4 lv = *(const float4*)&L[((long)bs * 8 + h) * 256 + lane * 4];
    float m = fmaxf(fmaxf(lv.x, lv.y), fmaxf(lv.z, lv.w));
    for (int o = 32; o; o >>= 1) m = fmaxf(m, __shfl_xor(m, o));
    float e0 = __expf(lv.x - m), e1 = __expf(lv.y - m);
    float e2 = __expf(lv.z - m), e3 = __expf(lv.w - m);
    float s = e0 + e1 + e2 + e3;
    for (int o = 32; o; o >>= 1) s += __shfl_xor(s, o);
    const float inv = 1.f / s;
    *(float4*)&p_s[h][lane * 4] = make_float4(e0 * inv, e1 * inv, e2 * inv, e3 * inv);
  }
  __syncthreads();

  const int d = dt * 128 + (t & 127);
  const int half = t >> 7;
  float acc[8] = {};
  const float* xb = x + ((long)bs * 256 + half * 128) * 512 + d;
#pragma unroll 8
  for (int n = 0; n < 128; ++n) {
    float xv = xb[(long)n * 512];
#pragma unroll
    for (int h = 0; h < 8; ++h)
      acc[h] += p_s[h][half * 128 + n] * xv;
  }
  if (half == 1) {
#pragma unroll
    for (int h = 0; h < 8; ++h) yp[h][t & 127] = acc[h];
  }
  __syncthreads();
  if (half == 0) {
#pragma unroll
    for (int h = 0; h < 8; ++h)
      Y[(long)bs * 4096 + h * 512 + d] = acc[h] + yp[h][t];
  }
}

extern "C" void kernel_launch(void* const* d_in, const int* in_sizes, int n_in,
                              void* d_out, int out_size, void* d_ws, size_t ws_size,
                              hipStream_t stream) {
  (void)in_sizes; (void)n_in; (void)out_size; (void)ws_size;
  const float* x  = (const float*)d_in[0];
  const float* Wq = (const float*)d_in[1];
  const float* bq = (const float*)d_in[2];
  const float* Wk = (const float*)d_in[3];
  const float* bk = (const float*)d_in[4];  (void)bk;  // softmax-invariant
  const float* Wv = (const float*)d_in[5];
  const float* bv = (const float*)d_in[6];
  const float* Wo = (const float*)d_in[7];
  const float* bo = (const float*)d_in[8];
  float* out = (float*)d_out;

  float* WkT = (float*)d_ws;       // 512*512  = 1 MiB
  float* q   = WkT + 262144;       // 256*512  = 0.5 MiB
  float* r   = q + 131072;         // 256*4096 = 4 MiB
  float* L   = r + 1048576;        // 256*8*256= 2 MiB
  float* Y   = L + 524288;         // 256*4096 = 4 MiB
  float* ctx = Y + 1048576;        // 256*512  = 0.5 MiB

  prep_kernel<<<768, 256, 0, stream>>>(x, Wq, bq, Wk, WkT, q);
  r_kernel<<<dim3(64, 8), 256, 0, stream>>>(q, WkT, r);
  logits_kernel<<<dim3(256, 8), 256, 0, stream>>>(x, r, L);
  y_kernel<<<dim3(256, 4), 256, 0, stream>>>(x, L, Y);
  gemm_ks_kernel<<<dim3(64, 8), 256, 0, stream>>>(Y, 4096L, 512, Wv, bv, ctx);
  gemm_ks_kernel<<<dim3(64, 8), 256, 0, stream>>>(ctx, 512L, 0, Wo, bo, out);
}